// Round 1
// baseline (2625.052 us; speedup 1.0000x reference)
//
#include <hip/hip_runtime.h>
#include <math.h>

#define B_ 1024
#define T_ 128
#define H_ 2048
#define C_ 10

typedef __bf16 bf16_t;
typedef __bf16 bf16x8 __attribute__((ext_vector_type(8)));
typedef __bf16 bf16x4 __attribute__((ext_vector_type(4)));
typedef float f32x4 __attribute__((ext_vector_type(4)));

// Static device storage: bf16 h ping-pong (8 MB), bf16 W_hh^T (8 MB),
// per-(t,bm) readiness counters (XCD-local handoff).
__device__ __align__(16) bf16_t g_hb[2][(size_t)B_ * H_];
__device__ __align__(16) bf16_t g_whhT[(size_t)H_ * H_];
__device__ int g_cnt[T_ * 8];   // [t][bm]; t=0 seeded to 32 by rnn_init

// AUX: cache policy. 0 = default; 1 = sc0 (force L1 miss -> read XCD L2).
template <int AUX>
__device__ __forceinline__ void gload16(const bf16_t* g, bf16_t* l) {
    __builtin_amdgcn_global_load_lds(
        (const __attribute__((address_space(1))) void*)g,
        (__attribute__((address_space(3))) void*)l, 16, 0, AUX);
}

// Counted-vmcnt barrier: retire oldest pipeline stage without draining.
template <int VM>
__device__ __forceinline__ void wait_vm_barrier() {
    asm volatile("s_waitcnt vmcnt(%0)\n\ts_barrier" :: "n"(VM) : "memory");
}

// One-time: W_hhT[n][k] = bf16(W_hh[k][n]) — B operand must be K-contiguous.
__global__ __launch_bounds__(256) void prep_whhT(const float* __restrict__ Whh) {
    __shared__ float tile[32][33];
    const int i  = threadIdx.x >> 3;
    const int j4 = (threadIdx.x & 7) * 4;
    const int r0 = blockIdx.y * 32;
    const int c0 = blockIdx.x * 32;
    f32x4 v = *(const f32x4*)(Whh + (size_t)(r0 + i) * H_ + c0 + j4);
    tile[i][j4 + 0] = v[0]; tile[i][j4 + 1] = v[1];
    tile[i][j4 + 2] = v[2]; tile[i][j4 + 3] = v[3];
    __syncthreads();
    bf16x4 o;
#pragma unroll
    for (int r = 0; r < 4; ++r) o[r] = (bf16_t)tile[j4 + r][i];
    *(bf16x4*)&g_whhT[(size_t)(c0 + i) * H_ + r0 + j4] = o;
}

// t = 0: h = tanh(x[:,0]*W_hx + b_h); also (re)initialize the counters.
__global__ __launch_bounds__(256) void rnn_init(const float* __restrict__ x,
                                                const float* __restrict__ Whx,
                                                const float* __restrict__ bh) {
    if (blockIdx.x == 0) {
        for (int i = threadIdx.x; i < T_ * 8; i += 256)
            g_cnt[i] = (i < 8) ? 32 : 0;   // g_cnt[0][*] = 32 (h0 ready)
    }
    const int gid = blockIdx.x * 256 + threadIdx.x;
    const int row = gid >> 9;
    const int col = (gid & 511) << 2;
    const float xv = x[(size_t)row * T_];
    f32x4 w = *(const f32x4*)&Whx[col];
    f32x4 b = *(const f32x4*)&bh[col];
    bf16x4 o;
#pragma unroll
    for (int j = 0; j < 4; ++j) o[j] = (bf16_t)tanhf(fmaf(xv, w[j], b[j]));
    *(bf16x4*)&g_hb[0][(size_t)row * H_ + col] = o;
}

// Persistent RNN, XCD-local sync. v2 restructure ("persistent-B registers"):
// the step-invariant W_hh^T tile (64 cols x 2048 K = 256 KB/block) lives
// ENTIRELY in VGPRs (256/lane), loaded once before the t-loop. This deletes
// the 64 MB/step of L2 B-traffic and stops B from thrashing the 4 MB XCD L2
// (so the A/h working set stays L2-resident). Waves are retiled 4x16-cols
// (wave tile 128x16) so the per-lane B footprint is exactly 256 VGPRs with
// no cross-wave duplication. LDS freed by dropping the B ring now holds the
// block's whole x slab (transposed), killing the per-step scalar x loads.
// A staging: 5-stage LDS ring (80 KB), 4 stages in flight, steady vmcnt(12).
__global__ __launch_bounds__(256, 1) void rnn_persist(const float* __restrict__ x,
                                                      const float* __restrict__ Whx,
                                                      const float* __restrict__ bh) {
    extern __shared__ __align__(16) bf16_t smem[];
    bf16_t* As = smem;                        // 5 stages x 8192 bf16 = 81920 B
    float*  xs = (float*)(smem + 5 * 8192);   // xs[t*128 + r], 65536 B

    const int tid  = threadIdx.x;
    const int lane = tid & 63;
    const int wave = tid >> 6;
    const int li  = blockIdx.x;
    const int bm  = li & 7;                          // == XCD (blk%8 map)
    const int bn  = li >> 3;                         // 0..31

    const int fr = lane & 15, fq = lane >> 4;

    // ---- one-time: x slab [128 rows x T_] -> xs transposed [t][row]
    for (int idx = tid; idx < 128 * (T_ / 4); idx += 256) {
        const int r  = idx >> 5;                     // row 0..127
        const int t4 = (idx & 31) * 4;               // t chunk
        f32x4 v = *(const f32x4*)(x + (size_t)(bm * 128 + r) * T_ + t4);
#pragma unroll
        for (int q = 0; q < 4; ++q) xs[(t4 + q) * 128 + r] = v[q];
    }

    // ---- one-time: persistent B fragments. Layout mirrors the old LDS
    // de-swizzled read: col = bn*64 + wave*16 + fr; k = it*64 + cc*32 + fq*8.
    const int bcol = bn * 64 + wave * 16 + fr;
    bf16x8 breg[32][2];
    {
        const bf16_t* gw = g_whhT + (size_t)bcol * H_ + fq * 8;
#pragma unroll
        for (int it = 0; it < 32; ++it)
#pragma unroll
            for (int cc = 0; cc < 2; ++cc)
                breg[it][cc] = *(const bf16x8*)(gw + it * 64 + cc * 32);
    }

    // A staging: linear slot s holds row s>>3, lds-chunk s&7;
    // global chunk = (s&7) ^ (row&7)  (8-row spread -> conflict-free reads).
    const int rA = tid >> 3;                         // 0..31
    const int cg = (tid & 7) ^ (rA & 7);
    const size_t aofsg = (size_t)(bm * 128 + rA) * H_ + cg * 8;

#define ISSUE_A(SLOT)                                                    \
    do {                                                                 \
        gload16<1>(gpa,            As + (SLOT) * 8192 + tid * 8);        \
        gload16<1>(gpa + 32 * H_,  As + (SLOT) * 8192 + (tid + 256) * 8);\
        gload16<1>(gpa + 64 * H_,  As + (SLOT) * 8192 + (tid + 512) * 8);\
        gload16<1>(gpa + 96 * H_,  As + (SLOT) * 8192 + (tid + 768) * 8);\
        gpa += 64;                                                       \
    } while (0)

    // frag read bases (elems): row fr, de-swizzled chunk (cc*4+fq)^(fr&7)
    const int cb0 = fr * 64 + ((0 + fq) ^ (fr & 7)) * 8;
    const int cb1 = fr * 64 + ((4 + fq) ^ (fr & 7)) * 8;

    f32x4 acc[8];

    // IT must be a literal (breg compile-time indexed; no scratch).
#define COMPUTE(SLOT, IT)                                                   \
    do {                                                                    \
        const bf16_t* ab = As + (SLOT) * 8192;                              \
        bf16x8 af[8];                                                       \
        _Pragma("unroll")                                                   \
        for (int i = 0; i < 8; ++i)                                         \
            af[i] = *(const bf16x8*)(ab + i * 1024 + cb0);                  \
        _Pragma("unroll")                                                   \
        for (int i = 0; i < 8; ++i)                                         \
            acc[i] = __builtin_amdgcn_mfma_f32_16x16x32_bf16(               \
                af[i], breg[IT][0], acc[i], 0, 0, 0);                       \
        _Pragma("unroll")                                                   \
        for (int i = 0; i < 8; ++i)                                         \
            af[i] = *(const bf16x8*)(ab + i * 1024 + cb1);                  \
        _Pragma("unroll")                                                   \
        for (int i = 0; i < 8; ++i)                                         \
            acc[i] = __builtin_amdgcn_mfma_f32_16x16x32_bf16(               \
                af[i], breg[IT][1], acc[i], 0, 0, 0);                       \
    } while (0)

    // epilogue constants (step-invariant)
    const float wv = Whx[bcol];
    const float bv = bh[bcol];

    __syncthreads();   // xs visible to all waves

#define ITER(ISS, CMP, IT)                                               \
    do { wait_vm_barrier<12>(); ISSUE_A(ISS); COMPUTE(CMP, IT); } while (0)

#pragma unroll 1
    for (int t = 1; t < T_; ++t) {
        const bf16_t* __restrict__ Abuf = g_hb[(t - 1) & 1];
        bf16_t* __restrict__ hn = g_hb[t & 1];
        const bf16_t* gpa = Abuf + aofsg;

        // wait until all 32 same-XCD writers of h-rows bm finished step t-1
        if (tid == 0) {
            while (__hip_atomic_load(&g_cnt[(t - 1) * 8 + bm], __ATOMIC_RELAXED,
                                     __HIP_MEMORY_SCOPE_AGENT) != 32)
                __builtin_amdgcn_s_sleep(2);
        }
        __syncthreads();          // no agent fence: sc0 A-loads read fresh L2

        ISSUE_A(0); ISSUE_A(1); ISSUE_A(2); ISSUE_A(3);   // chunks 0..3

#pragma unroll
        for (int i = 0; i < 8; ++i) acc[i] = (f32x4)(0.f);

        // 32 K-chunks, 5-slot ring, 4 stages in flight, steady vmcnt(12).
        ITER(4,0,0);  ITER(0,1,1);  ITER(1,2,2);  ITER(2,3,3);  ITER(3,4,4);
        ITER(4,0,5);  ITER(0,1,6);  ITER(1,2,7);  ITER(2,3,8);  ITER(3,4,9);
        ITER(4,0,10); ITER(0,1,11); ITER(1,2,12); ITER(2,3,13); ITER(3,4,14);
        ITER(4,0,15); ITER(0,1,16); ITER(1,2,17); ITER(2,3,18); ITER(3,4,19);
        ITER(4,0,20); ITER(0,1,21); ITER(1,2,22); ITER(2,3,23); ITER(3,4,24);
        ITER(4,0,25); ITER(0,1,26); ITER(1,2,27);
        wait_vm_barrier<12>(); COMPUTE(3,28);             // drain chunks 28..31
        wait_vm_barrier<8>();  COMPUTE(4,29);
        wait_vm_barrier<4>();  COMPUTE(0,30);
        wait_vm_barrier<0>();  COMPUTE(1,31);

        // epilogue: + x_t*W_hx + b_h, tanh, bf16 store (x from LDS)
#pragma unroll
        for (int i = 0; i < 8; ++i) {
            const int r0 = i * 16 + fq * 4;
            const f32x4 xq = *(const f32x4*)(xs + t * 128 + r0);
#pragma unroll
            for (int r = 0; r < 4; ++r)
                hn[(size_t)(bm * 128 + r0 + r) * H_ + bcol] =
                    (bf16_t)tanhf(acc[i][r] + xq[r] * wv + bv);
        }

        // publish: drain this wave's stores to L2, join waves, bump counter.
        asm volatile("s_waitcnt vmcnt(0)" ::: "memory");
        __syncthreads();
        if (tid == 0)
            __hip_atomic_fetch_add(&g_cnt[t * 8 + bm], 1, __ATOMIC_RELAXED,
                                   __HIP_MEMORY_SCOPE_AGENT);
    }
#undef ITER
#undef COMPUTE
#undef ISSUE_A
}

// p = h_T @ W_ph + b_p : one wave per batch row, fp32 accumulate.
__global__ __launch_bounds__(64) void rnn_proj(const float* __restrict__ Wph,
                                               const float* __restrict__ bp,
                                               float* __restrict__ out, int sb) {
    const int b = blockIdx.x;
    const int l = threadIdx.x;
    const bf16_t* h = g_hb[sb] + (size_t)b * H_;
    float acc[C_];
#pragma unroll
    for (int c = 0; c < C_; ++c) acc[c] = 0.f;
    for (int k = l; k < H_; k += 64) {
        const float hv = (float)h[k];
#pragma unroll
        for (int c = 0; c < C_; ++c)
            acc[c] = fmaf(hv, Wph[k * C_ + c], acc[c]);
    }
#pragma unroll
    for (int off = 32; off > 0; off >>= 1)
#pragma unroll
        for (int c = 0; c < C_; ++c) acc[c] += __shfl_down(acc[c], off);
    if (l == 0) {
#pragma unroll
        for (int c = 0; c < C_; ++c) out[b * C_ + c] = acc[c] + bp[c];
    }
}

extern "C" void kernel_launch(void* const* d_in, const int* in_sizes, int n_in,
                              void* d_out, int out_size, void* d_ws, size_t ws_size,
                              hipStream_t stream) {
    const float* x   = (const float*)d_in[0];   // [1024,128]
    const float* Whx = (const float*)d_in[1];   // [1,2048]
    const float* Whh = (const float*)d_in[2];   // [2048,2048]
    const float* bh  = (const float*)d_in[3];   // [2048]
    const float* Wph = (const float*)d_in[4];   // [2048,10]
    const float* bp  = (const float*)d_in[5];   // [1,10]
    float* out = (float*)d_out;                 // [1024,10]

    static bool attr_set = false;
    if (!attr_set) {
        hipFuncSetAttribute((const void*)rnn_persist,
                            hipFuncAttributeMaxDynamicSharedMemorySize, 147456);
        attr_set = true;
    }

    prep_whhT<<<dim3(64, 64), 256, 0, stream>>>(Whh);
    rnn_init<<<(B_ * H_ / 4) / 256, 256, 0, stream>>>(x, Whx, bh);
    rnn_persist<<<256, 256, 147456, stream>>>(x, Whx, bh);
    rnn_proj<<<B_, 64, 0, stream>>>(Wph, bp, out, (T_ - 1) & 1);
}